// Round 10
// baseline (145.842 us; speedup 1.0000x reference)
//
#include <hip/hip_runtime.h>
#include <hip/hip_bf16.h>

#define FEATS 768
#define HEADS 12
#define HD    64
#define BB    128
#define NN    197
#define M_TOT (BB * NN)   // 25216
#define SCALE_INV (3.6084391824351615e-02f)  // 1/sqrt(768)
#define VS    216          // Vtl row stride in shorts (432B = free 2-way banks)

typedef __bf16 bf16x8 __attribute__((ext_vector_type(8)));
typedef float  f32x4  __attribute__((ext_vector_type(4)));
typedef unsigned short u16x8 __attribute__((ext_vector_type(8)));

// NATIVE bf16 converts: (__bf16) cast = single HW v_cvt (RNE); compiler fuses
// pairs into v_cvt_pk_bf16_f32. (ROCm's __float2bfloat16 header fn is a
// multi-op software RNE sequence — ~330 converts/thread made it the VALU hog.)
__device__ __forceinline__ unsigned short f2bf1(float f) {
    __bf16 h = (__bf16)f;
    return *(unsigned short*)&h;
}
__device__ __forceinline__ unsigned int f2bf2(float lo, float hi) {
    return (unsigned int)f2bf1(lo) | ((unsigned int)f2bf1(hi) << 16);
}

// ---------------------------------------------------------------------------
// K0: W_qkv f32 [h][k][e] -> bf16 swizzled-transposed Wt_sw (validated R4+).
// ---------------------------------------------------------------------------
__global__ __launch_bounds__(256) void wqkvt_kernel(
    const float* __restrict__ Wqkv, unsigned short* __restrict__ Wt_sw)
{
    __shared__ float wl[64 * 192];
    const int t = threadIdx.x, h = blockIdx.x;
    const float* Wh = Wqkv + (long)h * (64 * 192);
    for (int i = t; i < 64 * 192; i += 256) wl[i] = Wh[i];
    __syncthreads();
    for (int c = t; c < 1536; c += 256) {
        int row = c >> 3, kc = (c & 7) ^ (row & 7);
        u16x8 v;
        #pragma unroll
        for (int j = 0; j < 8; ++j) v[j] = f2bf1(wl[(kc * 8 + j) * 192 + row]);
        *(u16x8*)&Wt_sw[(long)h * 12288 + c * 8] = v;
    }
}

// ---------------------------------------------------------------------------
// K1 v2: FUSED qkv + attention, q-SPLIT (validated R9 structure, unchanged
// except native bf16 casts). Block = (b, h, half), 256 thr, 77 KB LDS ->
// 2 blocks/CU. Full K,V redundant per half; flash attention on half's q-rows.
// ---------------------------------------------------------------------------
__global__ __launch_bounds__(256, 2) void qkv_attn_fused(
    const float* __restrict__ x, const unsigned short* __restrict__ Wt_sw,
    const float* __restrict__ bqkv, unsigned short* __restrict__ attn)
{
    __shared__ __align__(16) char lds[78864];
    unsigned short* As  = (unsigned short*)lds;            // [208][8ch][8] 26624B
    unsigned short* Ws  = (unsigned short*)(lds + 26624);  // 1536 chunks  24576B
    unsigned short* Ql  = (unsigned short*)lds;            // [112][8ch][8] (alias As)
    unsigned short* Kl  = (unsigned short*)(lds + 14336);  // [208][8ch][8] (alias)
    unsigned short* Pl  = (unsigned short*)(lds + 40960);  // [112][40]     (alias)
    unsigned short* Vtl = (unsigned short*)(lds + 51200);  // [64][216]+pad 27664B

    const int t  = threadIdx.x;
    const int w  = t >> 6, l = t & 63;
    const int lr = l & 15, g = l >> 4, g4 = g * 4;
    const int b  = blockIdx.x, h = blockIdx.y;
    const int half = blockIdx.z;
    const int qbase = half * 7;              // first global q-frag
    const int NQ    = half ? 6 : 7;          // local q-frag count

    // ---- zero Vtl (incl pad): cols >=208 are read (masked) but never written
    {
        const uint4 z = {0, 0, 0, 0};
        #pragma unroll
        for (int it = 0; it < 7; ++it) {
            int idx = it * 256 + t;
            if (idx < 1729) *(uint4*)&Vtl[idx * 8] = z;
        }
    }
    // ---- stage As: 208 rows x 64 k bf16, XOR-swizzled chunks (rows>=197 = 0)
    #pragma unroll
    for (int it = 0; it < 7; ++it) {
        int p = it * 256 + t;
        if (p < 1664) {
            int row = p >> 3, kc = (p & 7) ^ (row & 7);
            uint4 pk = {0, 0, 0, 0};
            if (row < NN) {
                const float* src = x + ((long)b * NN + row) * FEATS + h * HD + kc * 8;
                const float4 x0 = *(const float4*)src;
                const float4 x1 = *(const float4*)(src + 4);
                pk.x = f2bf2(x0.x, x0.y); pk.y = f2bf2(x0.z, x0.w);
                pk.z = f2bf2(x1.x, x1.y); pk.w = f2bf2(x1.z, x1.w);
            }
            *(uint4*)&As[p * 8] = pk;
        }
    }
    // ---- stage Ws: 1536 chunks via global_load_lds
    const unsigned short* Wh = Wt_sw + (long)h * 12288;
    #pragma unroll
    for (int it = 0; it < 6; ++it) {
        const int cb = it * 256 + w * 64;
        __builtin_amdgcn_global_load_lds(
            (const __attribute__((address_space(1))) void*)(Wh + (cb + l) * 8),
            (__attribute__((address_space(3))) void*)(Ws + cb * 8),
            16, 0, 0);
    }
    __syncthreads();

    // ---- Phase A: wave w owns one 16-col frag each of q,k,v: e0 = j*64+w*16
    bf16x8 bfr[3][2];
    #pragma unroll
    for (int j = 0; j < 3; ++j) {
        const int rn = j * 64 + w * 16 + lr;
        #pragma unroll
        for (int ks = 0; ks < 2; ++ks)
            bfr[j][ks] = *(const bf16x8*)&Ws[(rn * 8 + ((ks * 4 + g) ^ (rn & 7))) * 8];
    }

    f32x4 aq[7], ak[13], av[13];
    {   // bias init: q/k swapped (rows=e), v unswapped (col=e=lr)
        const f32x4 bq = *(const f32x4*)&bqkv[h * 192 + w * 16 + g4];
        const f32x4 bk = *(const f32x4*)&bqkv[h * 192 + 64 + w * 16 + g4];
        const float bvv = bqkv[h * 192 + 128 + w * 16 + lr];
        #pragma unroll
        for (int mi = 0; mi < 7; ++mi) aq[mi] = bq;
        #pragma unroll
        for (int mi = 0; mi < 13; ++mi) {
            ak[mi] = bk;
            #pragma unroll
            for (int r = 0; r < 4; ++r) av[mi][r] = bvv;
        }
    }

    #pragma unroll
    for (int mi = 0; mi < 13; ++mi) {
        const int rA = mi * 16 + lr;
        bf16x8 a0 = *(const bf16x8*)&As[(rA * 8 + ((0 + g) ^ (rA & 7))) * 8];
        bf16x8 a1 = *(const bf16x8*)&As[(rA * 8 + ((4 + g) ^ (rA & 7))) * 8];
        ak[mi] = __builtin_amdgcn_mfma_f32_16x16x32_bf16(bfr[1][0], a0, ak[mi], 0, 0, 0);
        ak[mi] = __builtin_amdgcn_mfma_f32_16x16x32_bf16(bfr[1][1], a1, ak[mi], 0, 0, 0);
        av[mi] = __builtin_amdgcn_mfma_f32_16x16x32_bf16(a0, bfr[2][0], av[mi], 0, 0, 0);
        av[mi] = __builtin_amdgcn_mfma_f32_16x16x32_bf16(a1, bfr[2][1], av[mi], 0, 0, 0);
        // q: static acc index under uniform half-branch (rule #20)
        if (half == 0) {
            if (mi < 7) {
                aq[mi] = __builtin_amdgcn_mfma_f32_16x16x32_bf16(bfr[0][0], a0, aq[mi], 0, 0, 0);
                aq[mi] = __builtin_amdgcn_mfma_f32_16x16x32_bf16(bfr[0][1], a1, aq[mi], 0, 0, 0);
            }
        } else {
            if (mi >= 7) {
                aq[mi - 7] = __builtin_amdgcn_mfma_f32_16x16x32_bf16(bfr[0][0], a0, aq[mi - 7], 0, 0, 0);
                aq[mi - 7] = __builtin_amdgcn_mfma_f32_16x16x32_bf16(bfr[0][1], a1, aq[mi - 7], 0, 0, 0);
            }
        }
    }
    __syncthreads();   // all As/Ws reads done; Ql/Kl writes may proceed

    // ---- write q (local rows), k (global rows) swizzled; v -> Vtl
    const int ech = w * 16 + g4;             // e-offset within 64-col group
    const int qc_hi = ech >> 3, qc_lo = ech & 7;
    #pragma unroll
    for (int lmi = 0; lmi < 7; ++lmi) {
        if (lmi < NQ) {
            const int lm = lmi * 16 + lr;
            const int c = qc_hi ^ (lm & 7);
            uint2 pv;
            pv.x = f2bf2(aq[lmi][0], aq[lmi][1]);
            pv.y = f2bf2(aq[lmi][2], aq[lmi][3]);
            *(uint2*)&Ql[(lm * 8 + c) * 8 + qc_lo] = pv;
        }
    }
    #pragma unroll
    for (int mi = 0; mi < 13; ++mi) {
        {   // k
            const int m = mi * 16 + lr;
            const int c = qc_hi ^ (m & 7);
            uint2 pv;
            pv.x = f2bf2(ak[mi][0], ak[mi][1]);
            pv.y = f2bf2(ak[mi][2], ak[mi][3]);
            *(uint2*)&Kl[(m * 8 + c) * 8 + qc_lo] = pv;
        }
        {   // v: d = w*16+lr, 4 consecutive n
            const int d = w * 16 + lr;
            const int n0 = mi * 16 + g4;
            uint2 pv;
            pv.x = f2bf2(av[mi][0], av[mi][1]);
            pv.y = f2bf2(av[mi][2], av[mi][3]);
            *(uint2*)&Vtl[d * VS + n0] = pv;
        }
    }
    __syncthreads();

    // ---- Phase B: flash attention on this block's q-rows
    const int nm = ((w + 4) < NQ) ? 2 : 1;
    bf16x8 qf[2][2];
    #pragma unroll
    for (int mi = 0; mi < 2; ++mi) {
        if (mi < nm || mi == 0) {
            const int lm = (w + mi * 4) * 16 + lr;
            #pragma unroll
            for (int ks = 0; ks < 2; ++ks)
                qf[mi][ks] = *(const bf16x8*)&Ql[(lm * 8 + ((ks * 4 + g) ^ (lm & 7))) * 8];
        }
    }

    u16x8 ob;
    #pragma unroll
    for (int j = 0; j < 8; ++j) ob[j] = 0x3F80;   // bf16 1.0
    bf16x8 onesf = *(bf16x8*)&ob;

    f32x4 oacc[2][4] = {};
    f32x4 ssum[2] = {};

    for (int tt = 0; tt < 7; ++tt) {
        const int kv0 = tt * 32;
        const int NF2 = (tt == 6) ? 1 : 2;   // upper frag at tt=6 fully masked

        bf16x8 kf[2][2];
        #pragma unroll
        for (int nf2 = 0; nf2 < 2; ++nf2) {
            if (nf2 < NF2) {
                const int row = kv0 + nf2 * 16 + lr;
                #pragma unroll
                for (int ks = 0; ks < 2; ++ks)
                    kf[nf2][ks] = *(const bf16x8*)&Kl[(row * 8 + ((ks * 4 + g) ^ (row & 7))) * 8];
            }
        }

        f32x4 s[2][2] = {};
        #pragma unroll
        for (int mi = 0; mi < 2; ++mi) {
            if (mi < nm) {
                #pragma unroll
                for (int nf2 = 0; nf2 < 2; ++nf2) {
                    if (nf2 < NF2) {
                        s[mi][nf2] = __builtin_amdgcn_mfma_f32_16x16x32_bf16(
                            qf[mi][0], kf[nf2][0], s[mi][nf2], 0, 0, 0);
                        s[mi][nf2] = __builtin_amdgcn_mfma_f32_16x16x32_bf16(
                            qf[mi][1], kf[nf2][1], s[mi][nf2], 0, 0, 0);
                    }
                }
            }
        }

        #pragma unroll
        for (int mi = 0; mi < 2; ++mi) {
            if (mi < nm) {
                #pragma unroll
                for (int nf2 = 0; nf2 < 2; ++nf2) {
                    const bool valid = (kv0 + nf2 * 16 + lr) < NN;
                    #pragma unroll
                    for (int r = 0; r < 4; ++r) {
                        float p = __expf(s[mi][nf2][r] * SCALE_INV);
                        p = valid ? p : 0.f;
                        Pl[((w + mi * 4) * 16 + g4 + r) * 40 + nf2 * 16 + lr] = f2bf1(p);
                    }
                }
            }
        }

        bf16x8 vf[4];
        #pragma unroll
        for (int df = 0; df < 4; ++df)
            vf[df] = *(const bf16x8*)&Vtl[(df * 16 + lr) * VS + kv0 + g * 8];
        #pragma unroll
        for (int mi = 0; mi < 2; ++mi) {
            if (mi < nm) {
                bf16x8 pa = *(const bf16x8*)&Pl[((w + mi * 4) * 16 + lr) * 40 + g * 8];
                #pragma unroll
                for (int df = 0; df < 4; ++df)
                    oacc[mi][df] = __builtin_amdgcn_mfma_f32_16x16x32_bf16(
                        pa, vf[df], oacc[mi][df], 0, 0, 0);
                ssum[mi] = __builtin_amdgcn_mfma_f32_16x16x32_bf16(
                    pa, onesf, ssum[mi], 0, 0, 0);
            }
        }
    }

    #pragma unroll
    for (int mi = 0; mi < 2; ++mi) {
        if (mi < nm) {
            f32x4 inv;
            #pragma unroll
            for (int r = 0; r < 4; ++r) inv[r] = 1.0f / ssum[mi][r];
            #pragma unroll
            for (int df = 0; df < 4; ++df) {
                #pragma unroll
                for (int r = 0; r < 4; ++r) {
                    const int grow = (qbase + w + mi * 4) * 16 + g4 + r;
                    if (grow < NN)
                        attn[((long)b * NN + grow) * FEATS + h * HD + df * 16 + lr]
                            = f2bf1(oacc[mi][df][r] * inv[r]);
                }
            }
        }
    }
}

// ---------------------------------------------------------------------------
// K2.5: W_out f32 [k][n] -> bf16 transposed Wt [n][k]  (768x768, one-shot)
// ---------------------------------------------------------------------------
__global__ __launch_bounds__(256) void wtrans_kernel(
    const float* __restrict__ W, unsigned short* __restrict__ Wt)
{
    __shared__ float tile[32][33];
    const int t  = threadIdx.x;
    const int tx = t & 31, ty = t >> 5;
    const int kb = blockIdx.x * 32, nb = blockIdx.y * 32;
    for (int r = ty; r < 32; r += 8)
        tile[r][tx] = W[(long)(kb + r) * FEATS + nb + tx];
    __syncthreads();
    for (int r = ty; r < 32; r += 8)
        Wt[(long)(nb + r) * FEATS + kb + tx] = f2bf1(tile[tx][r]);
}

// ---------------------------------------------------------------------------
// K3: out-projection via MFMA (validated R6/R9 BN=128 config, unchanged).
// ---------------------------------------------------------------------------
__global__ __launch_bounds__(256) void outproj_mfma(
    const unsigned short* __restrict__ A,
    const unsigned short* __restrict__ Bt,
    const float* __restrict__ bout, float* __restrict__ out)
{
    __shared__ unsigned short As[128 * 32];
    __shared__ unsigned short Bs[128 * 32];

    const int t  = threadIdx.x;
    const int w  = t >> 6;
    const int l  = t & 63;
    const int m0 = blockIdx.y * 128;
    const int n0 = blockIdx.x * 128;
    const int wm = (w >> 1) * 64;
    const int wn = (w & 1) * 64;
    const int lr = l & 15;
    const int lk = l >> 4;

    f32x4 acc[4][4] = {};

    for (int k0 = 0; k0 < FEATS; k0 += 32) {
        #pragma unroll
        for (int c = 0; c < 2; ++c) {
            const int off = c * 4096 + t * 16;
            const int row = off >> 6;
            const int col = (off & 63) >> 1;
            const unsigned short* gA = A  + (long)(m0 + row) * FEATS + k0 + col;
            const unsigned short* gB = Bt + (long)(n0 + row) * FEATS + k0 + col;
            __builtin_amdgcn_global_load_lds(
                (const __attribute__((address_space(1))) void*)gA,
                (__attribute__((address_space(3))) void*)(As + c * 2048 + w * 512),
                16, 0, 0);
            __builtin_amdgcn_global_load_lds(
                (const __attribute__((address_space(1))) void*)gB,
                (__attribute__((address_space(3))) void*)(Bs + c * 2048 + w * 512),
                16, 0, 0);
        }
        __syncthreads();

        bf16x8 af[4], bfr[4];
        #pragma unroll
        for (int mi = 0; mi < 4; ++mi)
            af[mi] = *(const bf16x8*)(As + (wm + mi * 16 + lr) * 32 + lk * 8);
        #pragma unroll
        for (int ni = 0; ni < 4; ++ni)
            bfr[ni] = *(const bf16x8*)(Bs + (wn + ni * 16 + lr) * 32 + lk * 8);
        #pragma unroll
        for (int mi = 0; mi < 4; ++mi)
            #pragma unroll
            for (int ni = 0; ni < 4; ++ni)
                acc[mi][ni] = __builtin_amdgcn_mfma_f32_16x16x32_bf16(
                    af[mi], bfr[ni], acc[mi][ni], 0, 0, 0);
        __syncthreads();
    }

    float bv[4];
    #pragma unroll
    for (int ni = 0; ni < 4; ++ni) bv[ni] = bout[n0 + wn + ni * 16 + lr];
    #pragma unroll
    for (int mi = 0; mi < 4; ++mi) {
        #pragma unroll
        for (int ni = 0; ni < 4; ++ni) {
            const int gcol = n0 + wn + ni * 16 + lr;
            #pragma unroll
            for (int r = 0; r < 4; ++r) {
                const int grow = m0 + wm + mi * 16 + lk * 4 + r;
                out[(long)grow * FEATS + gcol] = acc[mi][ni][r] + bv[ni];
            }
        }
    }
}

// ---------------------------------------------------------------------------
extern "C" void kernel_launch(void* const* d_in, const int* in_sizes, int n_in,
                              void* d_out, int out_size, void* d_ws, size_t ws_size,
                              hipStream_t stream)
{
    const float* x    = (const float*)d_in[0];
    const float* Wqkv = (const float*)d_in[1];
    const float* bqkv = (const float*)d_in[2];
    const float* Wout = (const float*)d_in[3];
    const float* bout = (const float*)d_in[4];
    float* out = (float*)d_out;

    // ws: attn (bf16 [M][768]) | Wt_sw (qkv weights, swizzled) | Wt (outproj)
    unsigned short* wsp = (unsigned short*)d_ws;
    const long S = (long)M_TOT * FEATS;               // 19,365,888
    unsigned short* attn  = wsp;
    unsigned short* Wt_sw = wsp + S;                  // 147,456 shorts
    unsigned short* Wt    = wsp + S + 150000;         // 589,824 shorts

    wqkvt_kernel<<<dim3(HEADS), 256, 0, stream>>>(Wqkv, Wt_sw);

    qkv_attn_fused<<<dim3(BB, HEADS, 2), 256, 0, stream>>>(x, Wt_sw, bqkv, attn);

    wtrans_kernel<<<dim3(FEATS / 32, FEATS / 32), 256, 0, stream>>>(Wout, Wt);

    outproj_mfma<<<dim3(FEATS / 128, M_TOT / 128), 256, 0, stream>>>(
        attn, Wt, bout, out);
}

// Round 11
// 119.872 us; speedup vs baseline: 1.2167x; 1.2167x over previous
//
#include <hip/hip_runtime.h>
#include <hip/hip_bf16.h>

#define FEATS 768
#define HEADS 12
#define HD    64
#define BB    128
#define NN    197
#define M_TOT (BB * NN)   // 25216
#define SCALE_INV (3.6084391824351615e-02f)  // 1/sqrt(768)
#define VS    216          // Vtl row stride in shorts

typedef __bf16 bf16x8 __attribute__((ext_vector_type(8)));
typedef float  f32x4  __attribute__((ext_vector_type(4)));
typedef unsigned short u16x8 __attribute__((ext_vector_type(8)));

__device__ __forceinline__ unsigned short f2bf1(float f) {
    __bf16 h = (__bf16)f;
    return *(unsigned short*)&h;
}
__device__ __forceinline__ unsigned int f2bf2(float lo, float hi) {
    return (unsigned int)f2bf1(lo) | ((unsigned int)f2bf1(hi) << 16);
}

// ---------------------------------------------------------------------------
// K0: W_qkv f32 [h][k][e] -> bf16 swizzled-transposed Wt_sw (validated R4+).
// ---------------------------------------------------------------------------
__global__ __launch_bounds__(256) void wqkvt_kernel(
    const float* __restrict__ Wqkv, unsigned short* __restrict__ Wt_sw)
{
    __shared__ float wl[64 * 192];
    const int t = threadIdx.x, h = blockIdx.x;
    const float* Wh = Wqkv + (long)h * (64 * 192);
    for (int i = t; i < 64 * 192; i += 256) wl[i] = Wh[i];
    __syncthreads();
    for (int c = t; c < 1536; c += 256) {
        int row = c >> 3, kc = (c & 7) ^ (row & 7);
        u16x8 v;
        #pragma unroll
        for (int j = 0; j < 8; ++j) v[j] = f2bf1(wl[(kc * 8 + j) * 192 + row]);
        *(u16x8*)&Wt_sw[(long)h * 12288 + c * 8] = v;
    }
}

// ---------------------------------------------------------------------------
// K1 v3: FUSED qkv + attention. One 512-thr block per (b,h); 80,912 B LDS
// -> 2 blocks/CU = 4 waves/SIMD (2x the latency cover of R9/R10's q-split),
// no redundant K/V compute, x read once.
// Phase A = R6's validated 512-thr qkv (waves = 2 row-groups x 4 col-groups).
// Pl ALIASES Ql (qf register-loaded + barrier first). Pl uses a zero-conflict
// chunk swizzle: write chunk c' = c ^ g (q-row's (q>>2)&3 == g per-instr),
// read chunk c' = g ^ ((lr>>2)&3); 16B-aligned pa reads.
// ---------------------------------------------------------------------------
__global__ __launch_bounds__(512, 4) void qkv_attn_fused(
    const float* __restrict__ x, const unsigned short* __restrict__ Wt_sw,
    const float* __restrict__ bqkv, unsigned short* __restrict__ attn)
{
    __shared__ __align__(16) char lds[80912];
    unsigned short* As  = (unsigned short*)lds;            // 1664 chunks of 8
    unsigned short* Ws  = (unsigned short*)(lds + 26624);  // 1536 chunks
    unsigned short* Ql  = (unsigned short*)lds;            // [208][8ch][8] (over As)
    unsigned short* Kl  = (unsigned short*)(lds + 26624);  // [208][8ch][8] (over Ws)
    unsigned short* Vtl = (unsigned short*)(lds + 53248);  // [64][216] + pad
    unsigned short* Pl  = (unsigned short*)lds;            // [208][40] swz (over Ql)

    const int t  = threadIdx.x;
    const int w  = t >> 6, l = t & 63;
    const int lr = l & 15, g = l >> 4, g4 = g * 4;
    const int b  = blockIdx.x, h = blockIdx.y;

    // ---- zero Vtl arena (27664 B): unwritten cols stay finite/zero
    {
        const uint4 z = {0, 0, 0, 0};
        #pragma unroll
        for (int it = 0; it < 4; ++it) {
            int idx = it * 512 + t;
            if (idx < 1729) *(uint4*)&Vtl[idx * 8] = z;
        }
    }
    // ---- stage As: 208 rows x 64 k bf16, XOR-swizzled chunks (rows>=197 = 0)
    #pragma unroll
    for (int it = 0; it < 4; ++it) {
        int p = it * 512 + t;
        if (p < 1664) {
            int row = p >> 3, kc = (p & 7) ^ (row & 7);
            uint4 pk = {0, 0, 0, 0};
            if (row < NN) {
                const float* src = x + ((long)b * NN + row) * FEATS + h * HD + kc * 8;
                const float4 x0 = *(const float4*)src;
                const float4 x1 = *(const float4*)(src + 4);
                pk.x = f2bf2(x0.x, x0.y); pk.y = f2bf2(x0.z, x0.w);
                pk.z = f2bf2(x1.x, x1.y); pk.w = f2bf2(x1.z, x1.w);
            }
            *(uint4*)&As[p * 8] = pk;
        }
    }
    // ---- stage Ws: 1536 chunks via global_load_lds
    const unsigned short* Wh = Wt_sw + (long)h * 12288;
    #pragma unroll
    for (int it = 0; it < 3; ++it) {
        const int cb = it * 512 + w * 64;
        __builtin_amdgcn_global_load_lds(
            (const __attribute__((address_space(1))) void*)(Wh + (cb + l) * 8),
            (__attribute__((address_space(3))) void*)(Ws + cb * 8),
            16, 0, 0);
    }
    __syncthreads();

    // ---- Phase A compute (R6 validated): wave = (w>>2 row-group, w&3 col-group)
    const int wn0 = (w & 3) * 48;
    const int f0  = (w >> 2) * 7;            // 0 or 7
    const int nf_ = (w >> 2) ? 6 : 7;

    bf16x8 bfr[3][2];
    #pragma unroll
    for (int ni = 0; ni < 3; ++ni) {
        const int rn = wn0 + ni * 16 + lr;
        #pragma unroll
        for (int ks = 0; ks < 2; ++ks)
            bfr[ni][ks] = *(const bf16x8*)&Ws[(rn * 8 + ((ks * 4 + g) ^ (rn & 7))) * 8];
    }

    f32x4 acc[7][3];
    #pragma unroll
    for (int ni = 0; ni < 3; ++ni) {
        const int e0 = wn0 + ni * 16;
        if (e0 < 128) {       // swapped: D row = e = g4+r
            const f32x4 bq = *(const f32x4*)&bqkv[h * 192 + e0 + g4];
            #pragma unroll
            for (int mi = 0; mi < 7; ++mi) acc[mi][ni] = bq;
        } else {              // unswapped: D col = e = lr
            const float bq = bqkv[h * 192 + e0 + lr];
            #pragma unroll
            for (int mi = 0; mi < 7; ++mi)
                #pragma unroll
                for (int r = 0; r < 4; ++r) acc[mi][ni][r] = bq;
        }
    }

    #pragma unroll
    for (int mi = 0; mi < 7; ++mi) {
        if (mi < nf_) {
            const int rA = (f0 + mi) * 16 + lr;
            bf16x8 a0 = *(const bf16x8*)&As[(rA * 8 + ((0 + g) ^ (rA & 7))) * 8];
            bf16x8 a1 = *(const bf16x8*)&As[(rA * 8 + ((4 + g) ^ (rA & 7))) * 8];
            #pragma unroll
            for (int ni = 0; ni < 3; ++ni) {
                const int e0 = wn0 + ni * 16;
                if (e0 < 128) {
                    acc[mi][ni] = __builtin_amdgcn_mfma_f32_16x16x32_bf16(
                        bfr[ni][0], a0, acc[mi][ni], 0, 0, 0);
                    acc[mi][ni] = __builtin_amdgcn_mfma_f32_16x16x32_bf16(
                        bfr[ni][1], a1, acc[mi][ni], 0, 0, 0);
                } else {
                    acc[mi][ni] = __builtin_amdgcn_mfma_f32_16x16x32_bf16(
                        a0, bfr[ni][0], acc[mi][ni], 0, 0, 0);
                    acc[mi][ni] = __builtin_amdgcn_mfma_f32_16x16x32_bf16(
                        a1, bfr[ni][1], acc[mi][ni], 0, 0, 0);
                }
            }
        }
    }
    __syncthreads();   // all As/Ws reads done; Ql/Kl/Vtl writes may proceed

    // ---- write q/k (XOR-chunk swizzled) and v (Vtl [d][n], stride 216)
    #pragma unroll
    for (int mi = 0; mi < 7; ++mi) {
        if (mi < nf_) {
            const int m = (f0 + mi) * 16 + lr;     // token row (q/k swapped)
            #pragma unroll
            for (int ni = 0; ni < 3; ++ni) {
                const int e0 = wn0 + ni * 16;
                uint2 pv;
                pv.x = f2bf2(acc[mi][ni][0], acc[mi][ni][1]);
                pv.y = f2bf2(acc[mi][ni][2], acc[mi][ni][3]);
                if (e0 < 64) {
                    const int c = ((e0 + g4) >> 3) ^ (m & 7);
                    *(uint2*)&Ql[(m * 8 + c) * 8 + (g4 & 7)] = pv;
                } else if (e0 < 128) {
                    const int e = e0 - 64 + g4;
                    const int c = (e >> 3) ^ (m & 7);
                    *(uint2*)&Kl[(m * 8 + c) * 8 + (g4 & 7)] = pv;
                } else {
                    const int d = e0 - 128 + lr;       // one d, 4 consecutive n
                    const int n0 = (f0 + mi) * 16 + g4;
                    *(uint2*)&Vtl[d * VS + n0] = pv;
                }
            }
        }
    }
    __syncthreads();

    // ---- Phase B: load qf from Ql, then Pl may alias Ql
    const int nm = (w < 5) ? 2 : 1;        // frags {w, w+8}, 13 total
    bf16x8 qf[2][2];
    #pragma unroll
    for (int mi = 0; mi < 2; ++mi) {
        if (mi == 0 || mi < nm) {
            const int lm = (w + mi * 8) * 16 + lr;
            #pragma unroll
            for (int ks = 0; ks < 2; ++ks)
                qf[mi][ks] = *(const bf16x8*)&Ql[(lm * 8 + ((ks * 4 + g) ^ (lm & 7))) * 8];
        }
    }
    __syncthreads();   // everyone's qf loaded; Pl writes may overwrite Ql

    u16x8 ob;
    #pragma unroll
    for (int j = 0; j < 8; ++j) ob[j] = 0x3F80;   // bf16 1.0
    bf16x8 onesf = *(bf16x8*)&ob;

    f32x4 oacc[2][4] = {};
    f32x4 ssum[2] = {};

    for (int tt = 0; tt < 7; ++tt) {
        const int kv0 = tt * 32;
        const int NF2 = (tt == 6) ? 1 : 2;   // upper frag at tt=6 fully masked

        bf16x8 kf[2][2];
        #pragma unroll
        for (int nf2 = 0; nf2 < 2; ++nf2) {
            if (nf2 < NF2) {
                const int row = kv0 + nf2 * 16 + lr;
                #pragma unroll
                for (int ks = 0; ks < 2; ++ks)
                    kf[nf2][ks] = *(const bf16x8*)&Kl[(row * 8 + ((ks * 4 + g) ^ (row & 7))) * 8];
            }
        }

        f32x4 s[2][2] = {};
        #pragma unroll
        for (int mi = 0; mi < 2; ++mi) {
            if (mi < nm) {
                #pragma unroll
                for (int nf2 = 0; nf2 < 2; ++nf2) {
                    if (nf2 < NF2) {
                        s[mi][nf2] = __builtin_amdgcn_mfma_f32_16x16x32_bf16(
                            qf[mi][0], kf[nf2][0], s[mi][nf2], 0, 0, 0);
                        s[mi][nf2] = __builtin_amdgcn_mfma_f32_16x16x32_bf16(
                            qf[mi][1], kf[nf2][1], s[mi][nf2], 0, 0, 0);
                    }
                }
            }
        }

        // exp + mask + swizzled Pl write (s[mi][1]=0 at tt=6 -> masked to 0)
        #pragma unroll
        for (int mi = 0; mi < 2; ++mi) {
            if (mi < nm) {
                #pragma unroll
                for (int nf2 = 0; nf2 < 2; ++nf2) {
                    const bool valid = (kv0 + nf2 * 16 + lr) < NN;
                    const int c = nf2 * 2 + (lr >> 3);
                    #pragma unroll
                    for (int r = 0; r < 4; ++r) {
                        float p = __expf(s[mi][nf2][r] * SCALE_INV);
                        p = valid ? p : 0.f;
                        const int q = (w + mi * 8) * 16 + g4 + r;
                        Pl[q * 40 + (c ^ g) * 8 + (lr & 7)] = f2bf1(p);
                    }
                }
            }
        }

        bf16x8 vf[4];
        #pragma unroll
        for (int df = 0; df < 4; ++df)
            vf[df] = *(const bf16x8*)&Vtl[(df * 16 + lr) * VS + kv0 + g * 8];
        #pragma unroll
        for (int mi = 0; mi < 2; ++mi) {
            if (mi < nm) {
                const int q = (w + mi * 8) * 16 + lr;
                bf16x8 pa = *(const bf16x8*)&Pl[q * 40 + (g ^ ((lr >> 2) & 3)) * 8];
                #pragma unroll
                for (int df = 0; df < 4; ++df)
                    oacc[mi][df] = __builtin_amdgcn_mfma_f32_16x16x32_bf16(
                        pa, vf[df], oacc[mi][df], 0, 0, 0);
                ssum[mi] = __builtin_amdgcn_mfma_f32_16x16x32_bf16(
                    pa, onesf, ssum[mi], 0, 0, 0);
            }
        }
    }

    #pragma unroll
    for (int mi = 0; mi < 2; ++mi) {
        if (mi < nm) {
            f32x4 inv;
            #pragma unroll
            for (int r = 0; r < 4; ++r) inv[r] = 1.0f / ssum[mi][r];
            #pragma unroll
            for (int df = 0; df < 4; ++df) {
                #pragma unroll
                for (int r = 0; r < 4; ++r) {
                    const int grow = (w + mi * 8) * 16 + g4 + r;
                    if (grow < NN)
                        attn[((long)b * NN + grow) * FEATS + h * HD + df * 16 + lr]
                            = f2bf1(oacc[mi][df][r] * inv[r]);
                }
            }
        }
    }
}

// ---------------------------------------------------------------------------
// K2.5: W_out f32 [k][n] -> bf16 transposed Wt [n][k]  (768x768, one-shot)
// ---------------------------------------------------------------------------
__global__ __launch_bounds__(256) void wtrans_kernel(
    const float* __restrict__ W, unsigned short* __restrict__ Wt)
{
    __shared__ float tile[32][33];
    const int t  = threadIdx.x;
    const int tx = t & 31, ty = t >> 5;
    const int kb = blockIdx.x * 32, nb = blockIdx.y * 32;
    for (int r = ty; r < 32; r += 8)
        tile[r][tx] = W[(long)(kb + r) * FEATS + nb + tx];
    __syncthreads();
    for (int r = ty; r < 32; r += 8)
        Wt[(long)(nb + r) * FEATS + kb + tx] = f2bf1(tile[tx][r]);
}

// ---------------------------------------------------------------------------
// K3: out-projection via MFMA (validated BN=128 structure) + bijective
// XCD swizzle (m204): the 6 n-blocks sharing an A-panel land on ONE XCD's
// L2 -> A re-fetch 232 MB -> ~40 MB. 1182 = 6*148 + 2*147.
// ---------------------------------------------------------------------------
__global__ __launch_bounds__(256) void outproj_mfma(
    const unsigned short* __restrict__ A,
    const unsigned short* __restrict__ Bt,
    const float* __restrict__ bout, float* __restrict__ out)
{
    __shared__ unsigned short As[128 * 32];
    __shared__ unsigned short Bs[128 * 32];

    const int t  = threadIdx.x;
    const int w  = t >> 6;
    const int l  = t & 63;
    const int idx  = blockIdx.x;             // 0..1181
    const int xcd  = idx & 7, qq = idx >> 3;
    const int start = (xcd < 6) ? xcd * 148 : 888 + (xcd - 6) * 147;
    const int wk = start + qq;
    const int m0 = (wk / 6) * 128;
    const int n0 = (wk % 6) * 128;
    const int wm = (w >> 1) * 64;
    const int wn = (w & 1) * 64;
    const int lr = l & 15;
    const int lk = l >> 4;

    f32x4 acc[4][4] = {};

    for (int k0 = 0; k0 < FEATS; k0 += 32) {
        #pragma unroll
        for (int c = 0; c < 2; ++c) {
            const int off = c * 4096 + t * 16;
            const int row = off >> 6;
            const int col = (off & 63) >> 1;
            const unsigned short* gA = A  + (long)(m0 + row) * FEATS + k0 + col;
            const unsigned short* gB = Bt + (long)(n0 + row) * FEATS + k0 + col;
            __builtin_amdgcn_global_load_lds(
                (const __attribute__((address_space(1))) void*)gA,
                (__attribute__((address_space(3))) void*)(As + c * 2048 + w * 512),
                16, 0, 0);
            __builtin_amdgcn_global_load_lds(
                (const __attribute__((address_space(1))) void*)gB,
                (__attribute__((address_space(3))) void*)(Bs + c * 2048 + w * 512),
                16, 0, 0);
        }
        __syncthreads();

        bf16x8 af[4], bfr[4];
        #pragma unroll
        for (int mi = 0; mi < 4; ++mi)
            af[mi] = *(const bf16x8*)(As + (wm + mi * 16 + lr) * 32 + lk * 8);
        #pragma unroll
        for (int ni = 0; ni < 4; ++ni)
            bfr[ni] = *(const bf16x8*)(Bs + (wn + ni * 16 + lr) * 32 + lk * 8);
        #pragma unroll
        for (int mi = 0; mi < 4; ++mi)
            #pragma unroll
            for (int ni = 0; ni < 4; ++ni)
                acc[mi][ni] = __builtin_amdgcn_mfma_f32_16x16x32_bf16(
                    af[mi], bfr[ni], acc[mi][ni], 0, 0, 0);
        __syncthreads();
    }

    float bv[4];
    #pragma unroll
    for (int ni = 0; ni < 4; ++ni) bv[ni] = bout[n0 + wn + ni * 16 + lr];
    #pragma unroll
    for (int mi = 0; mi < 4; ++mi) {
        #pragma unroll
        for (int ni = 0; ni < 4; ++ni) {
            const int gcol = n0 + wn + ni * 16 + lr;
            #pragma unroll
            for (int r = 0; r < 4; ++r) {
                const int grow = m0 + wm + mi * 16 + lk * 4 + r;
                out[(long)grow * FEATS + gcol] = acc[mi][ni][r] + bv[ni];
            }
        }
    }
}

// ---------------------------------------------------------------------------
extern "C" void kernel_launch(void* const* d_in, const int* in_sizes, int n_in,
                              void* d_out, int out_size, void* d_ws, size_t ws_size,
                              hipStream_t stream)
{
    const float* x    = (const float*)d_in[0];
    const float* Wqkv = (const float*)d_in[1];
    const float* bqkv = (const float*)d_in[2];
    const float* Wout = (const float*)d_in[3];
    const float* bout = (const float*)d_in[4];
    float* out = (float*)d_out;

    // ws: attn (bf16 [M][768]) | Wt_sw (qkv weights, swizzled) | Wt (outproj)
    unsigned short* wsp = (unsigned short*)d_ws;
    const long S = (long)M_TOT * FEATS;               // 19,365,888
    unsigned short* attn  = wsp;
    unsigned short* Wt_sw = wsp + S;                  // 147,456 shorts
    unsigned short* Wt    = wsp + S + 150000;         // 589,824 shorts

    wqkvt_kernel<<<dim3(HEADS), 256, 0, stream>>>(Wqkv, Wt_sw);

    qkv_attn_fused<<<dim3(BB, HEADS), 512, 0, stream>>>(x, Wt_sw, bqkv, attn);

    wtrans_kernel<<<dim3(FEATS / 32, FEATS / 32), 256, 0, stream>>>(Wout, Wt);

    outproj_mfma<<<dim3(1182), 256, 0, stream>>>(attn, Wt, bout, out);
}